// Round 4
// baseline (245.015 us; speedup 1.0000x reference)
//
#include <hip/hip_runtime.h>
#include <math.h>

#define BB 16
#define PP (768*768)        // 589824
#define NBINS 2048
#define CHUNKS 96           // blocks per image; pixels/block = 6144 (< 2^20: u64 20b fields safe)
#define KALL 176947         // int(P * 0.3)

#define LOV_LO (-17.0f)
#define LOV_RANGE 34.0f

typedef unsigned long long u64;

struct Acc {
  float pos_sum, pos_w, tpx, sprx, bce0;
  unsigned max_bce_bits, sum_t, n_tis;
  float lov_i, ft_i, ohem_i; unsigned posb;
  unsigned pad[4];          // 64 bytes
};

__device__ inline float wred_sum(float v) {
  #pragma unroll
  for (int o = 32; o > 0; o >>= 1) v += __shfl_down(v, o, 64);
  return v;
}
__device__ inline float wred_max(float v) {
  #pragma unroll
  for (int o = 32; o > 0; o >>= 1) v = fmaxf(v, __shfl_down(v, o, 64));
  return v;
}
__device__ inline unsigned wred_sumu(unsigned v) {
  #pragma unroll
  for (int o = 32; o > 0; o >>= 1) v += __shfl_down(v, o, 64);
  return v;
}

// ---------------- K1: fused elementwise pass; per-block partial hist, NO global atomics ----------------
// hist bin keyed by lovasz error e = 1 - l*(2t-1); packed u64:
//   count [0..19] | pos [20..39] | negtis [40..59]
__global__ __launch_bounds__(256) void k_main(const float* __restrict__ logits,
                                              const int* __restrict__ targets,
                                              const float* __restrict__ mask,
                                              Acc* __restrict__ acc,
                                              u64* __restrict__ partial)
{
  const int b = blockIdx.y;
  const int chunk = blockIdx.x;
  __shared__ u64 hist[NBINS];   // 16 KB
  for (int i = threadIdx.x; i < NBINS; i += 256) hist[i] = 0ull;

  const float4* l4 = (const float4*)(logits + (size_t)b * PP);
  const int4*   t4 = (const int4*)(targets + (size_t)b * PP);
  const float4* m4 = (const float4*)(mask + (size_t)b * PP);

  const float lov_scale = (float)NBINS / LOV_RANGE;

  // fallback loss_i[0]
  if (chunk == 0 && threadIdx.x == 0) {
    float l = logits[(size_t)b * PP];
    float tf = (float)targets[(size_t)b * PP];
    float m = mask[(size_t)b * PP];
    float ex = __expf(-fabsf(l));
    acc[b].bce0 = (fmaxf(l, 0.f) + __logf(1.f + ex) - l * tf) * m;
  }
  __syncthreads();

  float pos_sum = 0.f, pos_w = 0.f, tpa = 0.f, spra = 0.f, mx = 0.f;
  unsigned sum_t = 0, n_tis = 0;

  const int per_chunk4 = (PP / CHUNKS) / 4;          // 1536
  const int base4 = chunk * per_chunk4;
  const int iters = per_chunk4 / 256;                // 6

  // software pipeline: prefetch next iteration's vectors
  int i0 = base4 + threadIdx.x;
  float4 lv = l4[i0]; int4 tv = t4[i0]; float4 mv = m4[i0];

  for (int it = 0; it < iters; ++it) {
    float4 nlv; int4 ntv; float4 nmv;
    if (it + 1 < iters) {
      int i = base4 + (it + 1) * 256 + threadIdx.x;
      nlv = l4[i]; ntv = t4[i]; nmv = m4[i];
    }
    float ls[4] = {lv.x, lv.y, lv.z, lv.w};
    int   ts[4] = {tv.x, tv.y, tv.z, tv.w};
    float ms[4] = {mv.x, mv.y, mv.z, mv.w};
    #pragma unroll
    for (int c = 0; c < 4; ++c) {
      float l = ls[c]; int ti = ts[c]; float tf = (float)ti; float m = ms[c];
      float ex = __expf(-fabsf(l));                    // e^{-|l|}
      float lg = __logf(1.f + ex);                     // log1p via hw log (1+ex in (1,2])
      float loss = (fmaxf(l, 0.f) + lg - l * tf) * m;  // bce * mask
      float posw = tf * m;
      pos_sum = fmaf(loss, posw, pos_sum);
      pos_w  += posw;
      float pr = ((l >= 0.f) ? 1.f : ex) * __builtin_amdgcn_rcpf(1.f + ex);  // sigmoid
      spra += pr;
      tpa = fmaf(pr, tf, tpa);
      sum_t += (unsigned)ti;
      bool tis = (m == 1.0f);
      if (tis) { n_tis++; mx = fmaxf(mx, loss); }
      float s = fmaf(2.f, tf, -1.f);
      float e = fmaf(-l, s, 1.f);                      // lovasz error
      int bin = (int)((e - LOV_LO) * lov_scale);
      bin = bin < 0 ? 0 : (bin > NBINS - 1 ? NBINS - 1 : bin);
      u64 val = 1ull | ((u64)(unsigned)ti << 20) |
                ((u64)(unsigned)((ti == 0) & tis) << 40);
      atomicAdd(&hist[bin], val);
    }
    lv = nlv; tv = ntv; mv = nmv;
  }

  pos_sum = wred_sum(pos_sum); pos_w = wred_sum(pos_w);
  tpa = wred_sum(tpa); spra = wred_sum(spra);
  mx = wred_max(mx);
  sum_t = wred_sumu(sum_t); n_tis = wred_sumu(n_tis);
  if ((threadIdx.x & 63) == 0) {
    atomicAdd(&acc[b].pos_sum, pos_sum);
    atomicAdd(&acc[b].pos_w, pos_w);
    atomicAdd(&acc[b].tpx, tpa);
    atomicAdd(&acc[b].sprx, spra);
    atomicMax(&acc[b].max_bce_bits, __float_as_uint(mx));
    atomicAdd(&acc[b].sum_t, sum_t);
    atomicAdd(&acc[b].n_tis, n_tis);
  }

  __syncthreads();
  // non-atomic coalesced flush: partial[(b*CHUNKS+chunk)][bin]
  {
    u64* dst = partial + ((size_t)b * CHUNKS + chunk) * NBINS;
    ulonglong2* dst2 = (ulonglong2*)dst;
    const ulonglong2* src2 = (const ulonglong2*)hist;
    for (int i = threadIdx.x; i < NBINS / 2; i += 256) dst2[i] = src2[i];
  }
}

// ---------------- K1b: reduce per-block partials -> per-image hist ----------------
__global__ __launch_bounds__(256) void k_reduce(const u64* __restrict__ partial,
                                                u64* __restrict__ ghist)
{
  const int img = blockIdx.y;          // 16
  const int slice = blockIdx.x;        // 8 slices of 256 bins
  const int bin = slice * 256 + threadIdx.x;
  const u64* src = partial + (size_t)img * CHUNKS * NBINS + bin;
  u64 s0 = 0, s1 = 0, s2 = 0, s3 = 0;
  #pragma unroll 4
  for (int p = 0; p < CHUNKS; p += 4) {
    s0 += src[(size_t)(p + 0) * NBINS];
    s1 += src[(size_t)(p + 1) * NBINS];
    s2 += src[(size_t)(p + 2) * NBINS];
    s3 += src[(size_t)(p + 3) * NBINS];
  }
  ghist[(size_t)img * NBINS + bin] = (s0 + s1) + (s2 + s3);
}

// ---------------- K2: per-image single descending walk (lovasz + OHEM) ----------------
__global__ __launch_bounds__(256) void k_scan(Acc* __restrict__ acc,
                                              const u64* __restrict__ ghist)
{
  const int b = blockIdx.x;
  const int t = threadIdx.x;
  __shared__ unsigned sA[256], sB[256], sC[256];
  __shared__ float sf[256], sg[256];
  __shared__ unsigned ng_total_sh;

  const u64* gh = ghist + (size_t)b * NBINS;

  const unsigned sum_t = acc[b].sum_t;
  const float p = (float)sum_t;
  const bool has_pos = sum_t > 0;
  const unsigned n_neg_total = (unsigned)PP - sum_t;
  const int CH = NBINS / 256;          // 8 bins per thread
  const float lov_d = LOV_RANGE / (float)NBINS;

  int n_pos = (int)acc[b].pos_w;       // truncation like astype(int32)
  int n_remain = KALL - n_pos; if (n_remain < 0) n_remain = 0;

  // per-thread chunk totals (reversed order: descending e)
  u64 loc[8];
  unsigned tc = 0, tq = 0, tn = 0;
  #pragma unroll
  for (int k = 0; k < 8; ++k) {
    u64 v = gh[NBINS - 1 - (t * CH + k)];
    loc[k] = v;
    tc += (unsigned)(v & 0xFFFFFu);
    tq += (unsigned)((v >> 20) & 0xFFFFFu);
    tn += (unsigned)((v >> 40) & 0xFFFFFu);
  }
  sA[t] = tc; sB[t] = tq; sC[t] = tn;
  __syncthreads();
  if (t == 0) {
    unsigned aI = 0, aC = 0, aN = 0;
    for (int i = 0; i < 256; i++) {
      unsigned ci = sA[i], qi = sB[i], ni = sC[i];
      sA[i] = aI; sB[i] = aC; sC[i] = aN;
      aI += ci; aC += qi; aN += ni;
    }
    ng_total_sh = aN;
  }
  __syncthreads();

  float lov_local = 0.f, ns_local = 0.f;
  {
    unsigned I = sA[t], C = sB[t], NG = sC[t];
    float Jprev = has_pos ? (1.f - (p - (float)C) / (p + (float)I - (float)C)) : 0.f;
    #pragma unroll
    for (int k = 0; k < 8; ++k) {
      int j = NBINS - 1 - (t * CH + k);
      u64 v = loc[k];
      unsigned c = (unsigned)(v & 0xFFFFFu);
      if (c) {
        unsigned q = (unsigned)((v >> 20) & 0xFFFFFu);
        unsigned ng = (unsigned)((v >> 40) & 0xFFFFFu);
        float e = LOV_LO + ((float)j + 0.5f) * lov_d;
        if (has_pos) {
          float re = fmaxf(e, 0.f);
          if (n_neg_total > 0) {
            I += c; C += q;
            float Jb = 1.f - (p - (float)C) / (p + (float)I - (float)C);
            lov_local += re * (Jb - Jprev);
            Jprev = Jb;
          } else {
            double hi = (double)I + (double)c;
            double s = (hi * (hi + 1.0) - (double)I * ((double)I + 1.0)) * 0.5 / (double)p;
            lov_local += re * (float)s;
            I += c;
          }
        }
        if (n_remain > 0 && ng) {
          long long rem = (long long)n_remain - (long long)NG;
          unsigned take = rem <= 0 ? 0u : (rem >= (long long)ng ? ng : (unsigned)rem);
          if (take) {
            float l = e - 1.f;                         // negatives: e = 1 + l
            float nloss = fmaxf(l, 0.f) + __logf(1.f + __expf(-fabsf(l)));
            ns_local += (float)take * nloss;
          }
          NG += ng;
        }
      }
    }
  }
  sf[t] = lov_local; sg[t] = ns_local; __syncthreads();
  for (int off = 128; off > 0; off >>= 1) {
    if (t < off) { sf[t] += sf[t + off]; sg[t] += sg[t + off]; }
    __syncthreads();
  }

  if (t == 0) {
    float lov = sf[0];
    float neg_sum = sg[0];
    unsigned kept = (n_remain > 0)
        ? ((unsigned)n_remain < ng_total_sh ? (unsigned)n_remain : ng_total_sh) : 0u;
    float cnt = (float)n_pos + (float)kept;
    float ohem;
    if (cnt > 0.f) ohem = (acc[b].pos_sum + neg_sum) / cnt;
    else ohem = (acc[b].n_tis > 0) ? __uint_as_float(acc[b].max_bce_bits) : acc[b].bce0;
    float tp = acc[b].tpx;
    float fn = p - tp;
    float fp = acc[b].sprx - tp;
    float tv = (tp + 1e-6f) / (tp + 0.3f * fn + 0.7f * fp + 1e-6f);
    float ft = powf(fmaxf(1.f - tv, 0.f), 1.33f);
    acc[b].lov_i = lov; acc[b].ft_i = ft; acc[b].ohem_i = ohem;
    acc[b].posb = has_pos ? 1u : 0u;
  }
}

// ---------------- K3: final combine ----------------
__global__ void k_final(const Acc* __restrict__ acc, float* __restrict__ out)
{
  if (threadIdx.x == 0 && blockIdx.x == 0) {
    float os = 0.f, fts = 0.f, lvs = 0.f; int np = 0;
    for (int b = 0; b < BB; b++) {
      os += acc[b].ohem_i;
      if (acc[b].posb) { np++; fts += acc[b].ft_i; lvs += acc[b].lov_i; }
    }
    float denom = (np > 0) ? (float)np : 1.f;
    float r = os / (float)BB;
    if (np > 0) r += fts / denom + 0.2f * (lvs / denom);
    out[0] = r;
  }
}

extern "C" void kernel_launch(void* const* d_in, const int* in_sizes, int n_in,
                              void* d_out, int out_size, void* d_ws, size_t ws_size,
                              hipStream_t stream) {
  const float* logits  = (const float*)d_in[0];
  const int*   targets = (const int*)d_in[1];
  const float* mask    = (const float*)d_in[2];
  float* out = (float*)d_out;

  char* ws = (char*)d_ws;
  Acc* acc = (Acc*)ws;                                  // 1 KB
  u64* ghist = (u64*)(ws + 1024);                       // 16*2048*8 = 256 KB
  u64* partial = (u64*)(ws + 1024 + (size_t)BB * NBINS * 8);  // 1536*2048*8 = 24 MB
  (void)in_sizes; (void)n_in; (void)out_size; (void)ws_size;

  hipMemsetAsync(ws, 0, 1024, stream);   // only acc needs zeroing

  dim3 g1(CHUNKS, BB, 1);   // 1536 blocks, 16KB LDS -> 6 blocks/CU resident
  k_main<<<g1, 256, 0, stream>>>(logits, targets, mask, acc, partial);
  dim3 g2(NBINS / 256, BB, 1);   // 8 x 16 = 128 blocks
  k_reduce<<<g2, 256, 0, stream>>>(partial, ghist);
  k_scan<<<BB, 256, 0, stream>>>(acc, ghist);
  k_final<<<1, 64, 0, stream>>>(acc, out);
}

// Round 5
// 166.820 us; speedup vs baseline: 1.4687x; 1.4687x over previous
//
#include <hip/hip_runtime.h>
#include <math.h>

#define BB 16
#define PP (768*768)        // 589824
#define NBINS 4096
#define CHUNKS 64           // blocks per image; pixels/block = 9216 (<16384: 14-bit counts)
#define KALL 176947         // int(P * 0.3)

#define LOV_LO (-17.0f)
#define LOV_RANGE 34.0f

typedef unsigned long long u64;

struct PAcc { float pos_sum, pos_w, tpx, sprx, mx, sum_t, n_tis, bce0; };   // 32 B
struct AccR { float lov_i, ft_i, ohem_i; unsigned posb; };                  // 16 B

__device__ inline float wred_sum(float v) {
  #pragma unroll
  for (int o = 32; o > 0; o >>= 1) v += __shfl_down(v, o, 64);
  return v;
}
__device__ inline float wred_max(float v) {
  #pragma unroll
  for (int o = 32; o > 0; o >>= 1) v = fmaxf(v, __shfl_down(v, o, 64));
  return v;
}

// ---------------- K1: fused pass; u32 LDS hists; non-atomic flush; no global atomics at all ----------------
__global__ __launch_bounds__(256) void k_main(const float* __restrict__ logits,
                                              const int* __restrict__ targets,
                                              const float* __restrict__ mask,
                                              PAcc* __restrict__ pacc,
                                              u64* __restrict__ partial)
{
  const int b = blockIdx.y;
  const int chunk = blockIdx.x;
  __shared__ unsigned hist1[NBINS];   // count | pos<<16   (16 KB)
  __shared__ unsigned hist2[NBINS];   // negtis            (16 KB)
  __shared__ float wsum[4][8];
  for (int i = threadIdx.x; i < NBINS; i += 256) { hist1[i] = 0u; hist2[i] = 0u; }
  __syncthreads();

  const float4* l4 = (const float4*)(logits + (size_t)b * PP);
  const int4*   t4 = (const int4*)(targets + (size_t)b * PP);
  const float4* m4 = (const float4*)(mask + (size_t)b * PP);

  const float lov_scale = (float)NBINS / LOV_RANGE;

  float pos_sum = 0.f, pos_w = 0.f, tpa = 0.f, spra = 0.f, mx = 0.f;
  float sum_t = 0.f, n_tis = 0.f, bce0 = 0.f;

  // fallback loss_i[0] (only chunk 0 / thread 0 contributes; block-sum propagates it)
  if (chunk == 0 && threadIdx.x == 0) {
    float l = logits[(size_t)b * PP];
    float tf = (float)targets[(size_t)b * PP];
    float m = mask[(size_t)b * PP];
    float ex = __expf(-fabsf(l));
    bce0 = (fmaxf(l, 0.f) + __logf(1.f + ex) - l * tf) * m;
  }

  const int per_chunk4 = (PP / CHUNKS) / 4;          // 2304
  const int base4 = chunk * per_chunk4;
  const int iters = per_chunk4 / 256;                // 9

  for (int it = 0; it < iters; ++it) {
    int i = base4 + it * 256 + threadIdx.x;
    float4 lv = l4[i]; int4 tv = t4[i]; float4 mv = m4[i];
    float ls[4] = {lv.x, lv.y, lv.z, lv.w};
    int   ts[4] = {tv.x, tv.y, tv.z, tv.w};
    float ms[4] = {mv.x, mv.y, mv.z, mv.w};
    #pragma unroll
    for (int c = 0; c < 4; ++c) {
      float l = ls[c]; int ti = ts[c]; float tf = (float)ti; float m = ms[c];
      float ex = __expf(-fabsf(l));                    // e^{-|l|}
      float lg = __logf(1.f + ex);                     // log1p(exp(-|l|)), 1+ex in (1,2]
      float loss = (fmaxf(l, 0.f) + lg - l * tf) * m;  // bce * mask
      float posw = tf * m;
      pos_sum = fmaf(loss, posw, pos_sum);
      pos_w  += posw;
      float pr = ((l >= 0.f) ? 1.f : ex) * __builtin_amdgcn_rcpf(1.f + ex);  // sigmoid
      spra += pr;
      tpa = fmaf(pr, tf, tpa);
      sum_t += tf;
      bool tis = (m == 1.0f);
      if (tis) { n_tis += 1.f; mx = fmaxf(mx, loss); }
      float s = fmaf(2.f, tf, -1.f);
      float e = fmaf(-l, s, 1.f);                      // lovasz error
      int bin = (int)((e - LOV_LO) * lov_scale);
      bin = bin < 0 ? 0 : (bin > NBINS - 1 ? NBINS - 1 : bin);
      atomicAdd(&hist1[bin], 1u | ((unsigned)ti << 16));
      if ((ti == 0) & tis) atomicAdd(&hist2[bin], 1u);
    }
  }

  // block-level scalar reduction -> pacc (non-atomic)
  {
    float v0 = wred_sum(pos_sum), v1 = wred_sum(pos_w), v2 = wred_sum(tpa);
    float v3 = wred_sum(spra), v4 = wred_max(mx), v5 = wred_sum(sum_t);
    float v6 = wred_sum(n_tis), v7 = wred_sum(bce0);
    int w = threadIdx.x >> 6, lane = threadIdx.x & 63;
    if (lane == 0) {
      wsum[w][0] = v0; wsum[w][1] = v1; wsum[w][2] = v2; wsum[w][3] = v3;
      wsum[w][4] = v4; wsum[w][5] = v5; wsum[w][6] = v6; wsum[w][7] = v7;
    }
  }
  __syncthreads();
  if (threadIdx.x == 0) {
    PAcc r;
    r.pos_sum = wsum[0][0] + wsum[1][0] + wsum[2][0] + wsum[3][0];
    r.pos_w   = wsum[0][1] + wsum[1][1] + wsum[2][1] + wsum[3][1];
    r.tpx     = wsum[0][2] + wsum[1][2] + wsum[2][2] + wsum[3][2];
    r.sprx    = wsum[0][3] + wsum[1][3] + wsum[2][3] + wsum[3][3];
    r.mx      = fmaxf(fmaxf(wsum[0][4], wsum[1][4]), fmaxf(wsum[2][4], wsum[3][4]));
    r.sum_t   = wsum[0][5] + wsum[1][5] + wsum[2][5] + wsum[3][5];
    r.n_tis   = wsum[0][6] + wsum[1][6] + wsum[2][6] + wsum[3][6];
    r.bce0    = wsum[0][7] + wsum[1][7] + wsum[2][7] + wsum[3][7];
    pacc[(size_t)b * CHUNKS + chunk] = r;
  }

  // non-atomic coalesced flush, repacked to 20-bit u64 fields
  {
    u64* dst = partial + ((size_t)b * CHUNKS + chunk) * NBINS;
    for (int i = threadIdx.x; i < NBINS; i += 256) {
      unsigned v = hist1[i], nt = hist2[i];
      dst[i] = (u64)(v & 0xFFFFu) | ((u64)(v >> 16) << 20) | ((u64)nt << 40);
    }
  }
}

// ---------------- K1b: reduce partials -> per-image hist; reduce pacc; zero ticket ----------------
__global__ __launch_bounds__(256) void k_reduce(const u64* __restrict__ partial,
                                                u64* __restrict__ ghist,
                                                const PAcc* __restrict__ pacc,
                                                PAcc* __restrict__ accImg,
                                                unsigned* __restrict__ ticket)
{
  const int img = blockIdx.y;          // 16
  const int slice = blockIdx.x;        // NBINS/256 = 16
  const int bin = slice * 256 + threadIdx.x;
  const u64* src = partial + (size_t)img * CHUNKS * NBINS + bin;
  u64 s0 = 0, s1 = 0, s2 = 0, s3 = 0;
  #pragma unroll 4
  for (int p = 0; p < CHUNKS; p += 4) {
    s0 += src[(size_t)(p + 0) * NBINS];
    s1 += src[(size_t)(p + 1) * NBINS];
    s2 += src[(size_t)(p + 2) * NBINS];
    s3 += src[(size_t)(p + 3) * NBINS];
  }
  ghist[(size_t)img * NBINS + bin] = (s0 + s1) + (s2 + s3);

  if (slice == 0 && threadIdx.x < 64) {
    int t = threadIdx.x;
    PAcc v;
    if (t < CHUNKS) v = pacc[(size_t)img * CHUNKS + t];
    else { v.pos_sum = v.pos_w = v.tpx = v.sprx = v.mx = v.sum_t = v.n_tis = v.bce0 = 0.f; }
    v.pos_sum = wred_sum(v.pos_sum); v.pos_w = wred_sum(v.pos_w);
    v.tpx = wred_sum(v.tpx); v.sprx = wred_sum(v.sprx);
    v.mx = wred_max(v.mx); v.sum_t = wred_sum(v.sum_t);
    v.n_tis = wred_sum(v.n_tis); v.bce0 = wred_sum(v.bce0);
    if (t == 0) accImg[img] = v;
  }
  if (slice == 0 && img == 0 && threadIdx.x == 0) *ticket = 0u;
}

// ---------------- K2: per-image descending walk (lovasz + OHEM) + last-block final combine ----------------
__global__ __launch_bounds__(256) void k_scan(const PAcc* __restrict__ accImg,
                                              const u64* __restrict__ ghist,
                                              AccR* __restrict__ acc,
                                              unsigned* __restrict__ ticket,
                                              float* __restrict__ out)
{
  const int b = blockIdx.x;
  const int t = threadIdx.x;
  __shared__ unsigned sA[256], sB[256], sC[256];
  __shared__ float sf[256], sg[256];
  __shared__ unsigned ng_total_sh;

  const u64* gh = ghist + (size_t)b * NBINS;
  const PAcc a = accImg[b];

  const unsigned sum_t = (unsigned)a.sum_t;
  const float p = (float)sum_t;
  const bool has_pos = sum_t > 0;
  const unsigned n_neg_total = (unsigned)PP - sum_t;
  const int CH = NBINS / 256;          // 16 bins per thread
  const float lov_d = LOV_RANGE / (float)NBINS;

  int n_pos = (int)a.pos_w;            // truncation like astype(int32)
  int n_remain = KALL - n_pos; if (n_remain < 0) n_remain = 0;

  u64 loc[16];
  unsigned tc = 0, tq = 0, tn = 0;
  #pragma unroll
  for (int k = 0; k < 16; ++k) {
    u64 v = gh[NBINS - 1 - (t * CH + k)];
    loc[k] = v;
    tc += (unsigned)(v & 0xFFFFFu);
    tq += (unsigned)((v >> 20) & 0xFFFFFu);
    tn += (unsigned)((v >> 40) & 0xFFFFFu);
  }
  sA[t] = tc; sB[t] = tq; sC[t] = tn;
  __syncthreads();
  if (t == 0) {
    unsigned aI = 0, aC = 0, aN = 0;
    for (int i = 0; i < 256; i++) {
      unsigned ci = sA[i], qi = sB[i], ni = sC[i];
      sA[i] = aI; sB[i] = aC; sC[i] = aN;
      aI += ci; aC += qi; aN += ni;
    }
    ng_total_sh = aN;
  }
  __syncthreads();

  float lov_local = 0.f, ns_local = 0.f;
  {
    unsigned I = sA[t], C = sB[t], NG = sC[t];
    float Jprev = has_pos ? (1.f - (p - (float)C) / (p + (float)I - (float)C)) : 0.f;
    #pragma unroll 4
    for (int k = 0; k < 16; ++k) {
      int j = NBINS - 1 - (t * CH + k);
      u64 v = loc[k];
      unsigned c = (unsigned)(v & 0xFFFFFu);
      if (c) {
        unsigned q = (unsigned)((v >> 20) & 0xFFFFFu);
        unsigned ng = (unsigned)((v >> 40) & 0xFFFFFu);
        float e = LOV_LO + ((float)j + 0.5f) * lov_d;
        if (has_pos) {
          float re = fmaxf(e, 0.f);
          if (n_neg_total > 0) {
            I += c; C += q;
            float Jb = 1.f - (p - (float)C) / (p + (float)I - (float)C);
            lov_local += re * (Jb - Jprev);
            Jprev = Jb;
          } else {
            double hi = (double)I + (double)c;
            double s = (hi * (hi + 1.0) - (double)I * ((double)I + 1.0)) * 0.5 / (double)p;
            lov_local += re * (float)s;
            I += c;
          }
        }
        if (n_remain > 0 && ng) {
          long long rem = (long long)n_remain - (long long)NG;
          unsigned take = rem <= 0 ? 0u : (rem >= (long long)ng ? ng : (unsigned)rem);
          if (take) {
            float l = e - 1.f;                         // negatives: e = 1 + l
            float nloss = fmaxf(l, 0.f) + __logf(1.f + __expf(-fabsf(l)));
            ns_local += (float)take * nloss;
          }
          NG += ng;
        }
      }
    }
  }
  sf[t] = lov_local; sg[t] = ns_local; __syncthreads();
  for (int off = 128; off > 0; off >>= 1) {
    if (t < off) { sf[t] += sf[t + off]; sg[t] += sg[t + off]; }
    __syncthreads();
  }

  if (t == 0) {
    float lov = sf[0];
    float neg_sum = sg[0];
    unsigned kept = (n_remain > 0)
        ? ((unsigned)n_remain < ng_total_sh ? (unsigned)n_remain : ng_total_sh) : 0u;
    float cnt = (float)n_pos + (float)kept;
    float ohem;
    if (cnt > 0.f) ohem = (a.pos_sum + neg_sum) / cnt;
    else ohem = (a.n_tis > 0.f) ? a.mx : a.bce0;
    float tp = a.tpx;
    float fn = p - tp;
    float fp = a.sprx - tp;
    float tv = (tp + 1e-6f) / (tp + 0.3f * fn + 0.7f * fp + 1e-6f);
    float ft = powf(fmaxf(1.f - tv, 0.f), 1.33f);
    acc[b].lov_i = lov; acc[b].ft_i = ft; acc[b].ohem_i = ohem;
    acc[b].posb = has_pos ? 1u : 0u;

    __threadfence();
    unsigned ret = atomicAdd(ticket, 1u);
    if (ret == BB - 1) {                 // last block: final combine
      __threadfence();
      volatile AccR* va = acc;
      float os = 0.f, fts = 0.f, lvs = 0.f; int np = 0;
      for (int i = 0; i < BB; i++) {
        os += va[i].ohem_i;
        if (va[i].posb) { np++; fts += va[i].ft_i; lvs += va[i].lov_i; }
      }
      float denom = (np > 0) ? (float)np : 1.f;
      float r = os / (float)BB;
      if (np > 0) r += fts / denom + 0.2f * (lvs / denom);
      out[0] = r;
    }
  }
}

extern "C" void kernel_launch(void* const* d_in, const int* in_sizes, int n_in,
                              void* d_out, int out_size, void* d_ws, size_t ws_size,
                              hipStream_t stream) {
  const float* logits  = (const float*)d_in[0];
  const int*   targets = (const int*)d_in[1];
  const float* mask    = (const float*)d_in[2];
  float* out = (float*)d_out;

  char* ws = (char*)d_ws;
  AccR*     acc     = (AccR*)ws;                       // 256 B
  unsigned* ticket  = (unsigned*)(ws + 256);           // 4 B
  PAcc*     accImg  = (PAcc*)(ws + 512);               // 512 B
  PAcc*     pacc    = (PAcc*)(ws + 1024);              // 1024*32 = 32 KB
  u64*      ghist   = (u64*)(ws + 64 * 1024);          // 16*4096*8 = 512 KB
  u64*      partial = (u64*)(ws + 1024 * 1024);        // 1024*4096*8 = 33.5 MB
  (void)in_sizes; (void)n_in; (void)out_size; (void)ws_size;

  // no memset: every ws location is written before it is read this launch

  dim3 g1(CHUNKS, BB, 1);        // 1024 blocks, 32KB LDS -> 4-5 blocks/CU
  k_main<<<g1, 256, 0, stream>>>(logits, targets, mask, pacc, partial);
  dim3 g2(NBINS / 256, BB, 1);   // 16 x 16 = 256 blocks
  k_reduce<<<g2, 256, 0, stream>>>(partial, ghist, pacc, accImg, ticket);
  k_scan<<<BB, 256, 0, stream>>>(accImg, ghist, acc, ticket, out);
}